// Round 1
// baseline (296.986 us; speedup 1.0000x reference)
//
#include <hip/hip_runtime.h>

#define DDIM 256
#define SEG_ROWS 512

// ---------------------------------------------------------------------------
// Segment-sum over sorted batch ids: S[g, :] += sum of x rows with batch==g.
// 256 threads = 4 waves; wave s owns rows r0+s, r0+s+4, ... (one float4 = 4
// columns per lane, 64 lanes cover the 256-col row). Register-accumulate runs
// of equal segment id; flush with atomicAdd at boundaries only.
// ---------------------------------------------------------------------------
__global__ __launch_bounds__(256) void segsum_kernel(
    const float* __restrict__ x, const int* __restrict__ batch,
    float* __restrict__ S, float* __restrict__ counts, int N) {
  __shared__ int sb[SEG_ROWS];
  const int r0 = blockIdx.x * SEG_ROWS;
  int nrows = N - r0;
  if (nrows > SEG_ROWS) nrows = SEG_ROWS;
  for (int i = threadIdx.x; i < nrows; i += 256) sb[i] = batch[r0 + i];
  __syncthreads();

  const int slot = threadIdx.x >> 6;        // wave id within block: 0..3
  const int c4   = (threadIdx.x & 63) << 2; // column base: 0..252 step 4
  float4 acc = make_float4(0.f, 0.f, 0.f, 0.f);
  int cur = -1, cnt = 0;

  for (int i = slot; i < nrows; i += 4) {
    const int seg = sb[i];                  // wave-uniform
    const float4 v =
        *reinterpret_cast<const float4*>(x + (size_t)(r0 + i) * DDIM + c4);
    if (seg != cur) {                       // wave-uniform branch
      if (cur >= 0) {
        float* p = S + (size_t)cur * DDIM + c4;
        atomicAdd(p + 0, acc.x);
        atomicAdd(p + 1, acc.y);
        atomicAdd(p + 2, acc.z);
        atomicAdd(p + 3, acc.w);
        if ((threadIdx.x & 63) == 0) atomicAdd(counts + cur, (float)cnt);
      }
      cur = seg;
      acc = v;
      cnt = 1;
    } else {
      acc.x += v.x; acc.y += v.y; acc.z += v.z; acc.w += v.w;
      ++cnt;
    }
  }
  if (cur >= 0) {
    float* p = S + (size_t)cur * DDIM + c4;
    atomicAdd(p + 0, acc.x);
    atomicAdd(p + 1, acc.y);
    atomicAdd(p + 2, acc.z);
    atomicAdd(p + 3, acc.w);
    if ((threadIdx.x & 63) == 0) atomicAdd(counts + cur, (float)cnt);
  }
}

// ---------------------------------------------------------------------------
// fp32 tiled GEMM: C[M,N] = A[M,K] @ B[K,N] + bias (optionally scaled by
// counts[row]) with optional ReLU. BM=BN=64, BK=16, 256 threads, 4x4 acc.
// A-tile stored transposed in LDS so both fragment reads are contiguous f4.
// ---------------------------------------------------------------------------
template <bool RELU, bool SCALED_BIAS>
__global__ __launch_bounds__(256) void gemm64_kernel(
    int M, int N, int K, const float* __restrict__ A,
    const float* __restrict__ B, const float* __restrict__ bias,
    const float* __restrict__ counts, float* __restrict__ C) {
  __shared__ float As[16][64];  // As[k][m]
  __shared__ float Bs[16][64];  // Bs[k][n]
  const int m0 = blockIdx.y * 64, n0 = blockIdx.x * 64;
  const int tid = threadIdx.x;
  const int tx = tid & 15, ty = tid >> 4;
  const int ar = tid >> 2, ac = (tid & 3) << 2;   // A-load: row, col4
  const int br = tid >> 4, bc = (tid & 15) << 2;  // B-load: row, col4

  float acc[4][4] = {};

  for (int k0 = 0; k0 < K; k0 += 16) {
    const float4 av =
        *reinterpret_cast<const float4*>(A + (size_t)(m0 + ar) * K + k0 + ac);
    const float4 bv =
        *reinterpret_cast<const float4*>(B + (size_t)(k0 + br) * N + n0 + bc);
    __syncthreads();  // previous tile's compute done before overwrite
    As[ac + 0][ar] = av.x;
    As[ac + 1][ar] = av.y;
    As[ac + 2][ar] = av.z;
    As[ac + 3][ar] = av.w;
    *reinterpret_cast<float4*>(&Bs[br][bc]) = bv;
    __syncthreads();
#pragma unroll
    for (int kk = 0; kk < 16; ++kk) {
      float a[4], b[4];
      *reinterpret_cast<float4*>(a) =
          *reinterpret_cast<const float4*>(&As[kk][ty << 2]);
      *reinterpret_cast<float4*>(b) =
          *reinterpret_cast<const float4*>(&Bs[kk][tx << 2]);
#pragma unroll
      for (int i = 0; i < 4; ++i)
#pragma unroll
        for (int j = 0; j < 4; ++j) acc[i][j] += a[i] * b[j];
    }
  }

  const float4 bias4 =
      *reinterpret_cast<const float4*>(bias + n0 + (tx << 2));
#pragma unroll
  for (int i = 0; i < 4; ++i) {
    const int row = m0 + (ty << 2) + i;
    const float s = SCALED_BIAS ? counts[row] : 1.0f;
    float4 r;
    r.x = acc[i][0] + s * bias4.x;
    r.y = acc[i][1] + s * bias4.y;
    r.z = acc[i][2] + s * bias4.z;
    r.w = acc[i][3] + s * bias4.w;
    if (RELU) {
      r.x = fmaxf(r.x, 0.f);
      r.y = fmaxf(r.y, 0.f);
      r.z = fmaxf(r.z, 0.f);
      r.w = fmaxf(r.w, 0.f);
    }
    *reinterpret_cast<float4*>(C + (size_t)row * N + n0 + (tx << 2)) = r;
  }
}

extern "C" void kernel_launch(void* const* d_in, const int* in_sizes, int n_in,
                              void* d_out, int out_size, void* d_ws,
                              size_t ws_size, hipStream_t stream) {
  const float* x    = (const float*)d_in[0];
  const int*   batch= (const int*)d_in[1];
  const float* W_in = (const float*)d_in[2];
  const float* b_in = (const float*)d_in[3];
  const float* W1   = (const float*)d_in[4];
  const float* b1   = (const float*)d_in[5];
  const float* W2   = (const float*)d_in[6];
  const float* b2   = (const float*)d_in[7];
  float* out = (float*)d_out;

  const int N = in_sizes[1];          // 1,000,000 rows
  const int G = out_size / DDIM;      // 4096 segments

  // Workspace layout (floats): S[G*D] | counts[G] | pooled[G*D] | H[G*2D]
  float* S      = (float*)d_ws;
  float* counts = S + (size_t)G * DDIM;
  float* pooled = counts + G;
  float* H      = pooled + (size_t)G * DDIM;

  // Zero the atomic-accumulated buffers (S + counts).
  hipMemsetAsync(d_ws, 0, ((size_t)G * DDIM + G) * sizeof(float), stream);

  // 1) S = segment_sum(x), counts = segment counts
  const int nblk = (N + SEG_ROWS - 1) / SEG_ROWS;
  segsum_kernel<<<nblk, 256, 0, stream>>>(x, batch, S, counts, N);

  // 2) pooled = S @ W_in + counts ⊗ b_in          [G, 256]
  {
    dim3 grid(DDIM / 64, G / 64);
    gemm64_kernel<false, true><<<grid, 256, 0, stream>>>(
        G, DDIM, DDIM, S, W_in, b_in, counts, pooled);
  }
  // 3) H = relu(pooled @ W1 + b1)                  [G, 512]
  {
    dim3 grid((2 * DDIM) / 64, G / 64);
    gemm64_kernel<true, false><<<grid, 256, 0, stream>>>(
        G, 2 * DDIM, DDIM, pooled, W1, b1, nullptr, H);
  }
  // 4) out = H @ W2 + b2                           [G, 256]
  {
    dim3 grid(DDIM / 64, G / 64);
    gemm64_kernel<false, false><<<grid, 256, 0, stream>>>(
        G, DDIM, 2 * DDIM, H, W2, b2, nullptr, out);
  }
}

// Round 2
// 284.890 us; speedup vs baseline: 1.0425x; 1.0425x over previous
//
#include <hip/hip_runtime.h>

#define DDIM 256

// ---------------------------------------------------------------------------
// Segment-sum, one block per segment (batch is sorted). Binary-search the
// row range [start,end) for segment g, register-accumulate float4 column
// slices across 4 waves, LDS-reduce, store directly (no atomics, no memset).
// ---------------------------------------------------------------------------
__global__ __launch_bounds__(256) void segsum_kernel(
    const float* __restrict__ x, const int* __restrict__ batch,
    float* __restrict__ S, float* __restrict__ counts, int N) {
  const int g = blockIdx.x;
  __shared__ int se[2];
  __shared__ float red[3][DDIM];

  if (threadIdx.x < 2) {
    const int target = g + threadIdx.x;
    int lo = 0, hi = N;
    while (lo < hi) {
      const int mid = (lo + hi) >> 1;
      if (batch[mid] < target) lo = mid + 1;
      else hi = mid;
    }
    se[threadIdx.x] = lo;
  }
  __syncthreads();
  const int start = se[0], end = se[1];

  const int w  = threadIdx.x >> 6;          // wave 0..3
  const int c4 = (threadIdx.x & 63) << 2;   // column base

  float4 a0 = make_float4(0.f, 0.f, 0.f, 0.f);
  float4 a1 = make_float4(0.f, 0.f, 0.f, 0.f);
  int i = start + w;
  for (; i + 4 < end; i += 8) {
    const float4 v0 = *reinterpret_cast<const float4*>(x + (size_t)i * DDIM + c4);
    const float4 v1 = *reinterpret_cast<const float4*>(x + (size_t)(i + 4) * DDIM + c4);
    a0.x += v0.x; a0.y += v0.y; a0.z += v0.z; a0.w += v0.w;
    a1.x += v1.x; a1.y += v1.y; a1.z += v1.z; a1.w += v1.w;
  }
  if (i < end) {
    const float4 v0 = *reinterpret_cast<const float4*>(x + (size_t)i * DDIM + c4);
    a0.x += v0.x; a0.y += v0.y; a0.z += v0.z; a0.w += v0.w;
  }
  a0.x += a1.x; a0.y += a1.y; a0.z += a1.z; a0.w += a1.w;

  if (w != 0) *reinterpret_cast<float4*>(&red[w - 1][c4]) = a0;
  __syncthreads();
  if (w == 0) {
#pragma unroll
    for (int r = 0; r < 3; ++r) {
      const float4 v = *reinterpret_cast<const float4*>(&red[r][c4]);
      a0.x += v.x; a0.y += v.y; a0.z += v.z; a0.w += v.w;
    }
    *reinterpret_cast<float4*>(S + (size_t)g * DDIM + c4) = a0;
    if (threadIdx.x == 0) counts[g] = (float)(end - start);
  }
}

// ---------------------------------------------------------------------------
// bvec[j] = sum_k b_in[k] * W1[k][j]   (W1 is [256, 512] row-major)
// ---------------------------------------------------------------------------
__global__ __launch_bounds__(256) void bvec_kernel(
    const float* __restrict__ b_in, const float* __restrict__ W1,
    float* __restrict__ bvec) {
  const int j = blockIdx.x * 256 + threadIdx.x;  // grid 2 blocks -> 512 cols
  float s = 0.f;
#pragma unroll 8
  for (int k = 0; k < DDIM; ++k) s += b_in[k] * W1[(size_t)k * 512 + j];
  bvec[j] = s;
}

// ---------------------------------------------------------------------------
// fp32 tiled GEMM: C[M,N] = op(A[M,K] @ B[K,N] + bias). BM=BN=64, BK=16,
// 256 threads, 4x4 acc, A-tile transposed in LDS.
// BIAS_MODE: 0 = none, 1 = +bias[j], 2 = +counts[row]*bvec[j] + bias[j]
// ---------------------------------------------------------------------------
template <bool RELU, int BIAS_MODE>
__global__ __launch_bounds__(256) void gemm64_kernel(
    int M, int N, int K, const float* __restrict__ A,
    const float* __restrict__ B, const float* __restrict__ bias,
    const float* __restrict__ bvec, const float* __restrict__ counts,
    float* __restrict__ C) {
  __shared__ float As[16][64];  // As[k][m]
  __shared__ float Bs[16][64];  // Bs[k][n]
  const int m0 = blockIdx.y * 64, n0 = blockIdx.x * 64;
  const int tid = threadIdx.x;
  const int tx = tid & 15, ty = tid >> 4;
  const int ar = tid >> 2, ac = (tid & 3) << 2;   // A-load: row, col4
  const int br = tid >> 4, bc = (tid & 15) << 2;  // B-load: row, col4

  float acc[4][4] = {};

  for (int k0 = 0; k0 < K; k0 += 16) {
    const float4 av =
        *reinterpret_cast<const float4*>(A + (size_t)(m0 + ar) * K + k0 + ac);
    const float4 bv =
        *reinterpret_cast<const float4*>(B + (size_t)(k0 + br) * N + n0 + bc);
    __syncthreads();
    As[ac + 0][ar] = av.x;
    As[ac + 1][ar] = av.y;
    As[ac + 2][ar] = av.z;
    As[ac + 3][ar] = av.w;
    *reinterpret_cast<float4*>(&Bs[br][bc]) = bv;
    __syncthreads();
#pragma unroll
    for (int kk = 0; kk < 16; ++kk) {
      float a[4], b[4];
      *reinterpret_cast<float4*>(a) =
          *reinterpret_cast<const float4*>(&As[kk][ty << 2]);
      *reinterpret_cast<float4*>(b) =
          *reinterpret_cast<const float4*>(&Bs[kk][tx << 2]);
#pragma unroll
      for (int i = 0; i < 4; ++i)
#pragma unroll
        for (int j = 0; j < 4; ++j) acc[i][j] += a[i] * b[j];
    }
  }

  float4 bias4 = make_float4(0.f, 0.f, 0.f, 0.f);
  float4 bvec4 = make_float4(0.f, 0.f, 0.f, 0.f);
  if (BIAS_MODE >= 1)
    bias4 = *reinterpret_cast<const float4*>(bias + n0 + (tx << 2));
  if (BIAS_MODE == 2)
    bvec4 = *reinterpret_cast<const float4*>(bvec + n0 + (tx << 2));

#pragma unroll
  for (int i = 0; i < 4; ++i) {
    const int row = m0 + (ty << 2) + i;
    float cnt = 0.f;
    if (BIAS_MODE == 2) cnt = counts[row];
    float4 r;
    r.x = acc[i][0] + bias4.x + cnt * bvec4.x;
    r.y = acc[i][1] + bias4.y + cnt * bvec4.y;
    r.z = acc[i][2] + bias4.z + cnt * bvec4.z;
    r.w = acc[i][3] + bias4.w + cnt * bvec4.w;
    if (RELU) {
      r.x = fmaxf(r.x, 0.f);
      r.y = fmaxf(r.y, 0.f);
      r.z = fmaxf(r.z, 0.f);
      r.w = fmaxf(r.w, 0.f);
    }
    *reinterpret_cast<float4*>(C + (size_t)row * N + n0 + (tx << 2)) = r;
  }
}

extern "C" void kernel_launch(void* const* d_in, const int* in_sizes, int n_in,
                              void* d_out, int out_size, void* d_ws,
                              size_t ws_size, hipStream_t stream) {
  const float* x     = (const float*)d_in[0];
  const int*   batch = (const int*)d_in[1];
  const float* W_in  = (const float*)d_in[2];
  const float* b_in  = (const float*)d_in[3];
  const float* W1    = (const float*)d_in[4];
  const float* b1    = (const float*)d_in[5];
  const float* W2    = (const float*)d_in[6];
  const float* b2    = (const float*)d_in[7];
  float* out = (float*)d_out;

  const int N = in_sizes[1];       // 1,000,000 rows
  const int G = out_size / DDIM;   // 4096 segments

  // Workspace (floats): S[G*256] | counts[G] | H[G*512] | Wfused[256*512] | bvec[512]
  float* S      = (float*)d_ws;
  float* counts = S + (size_t)G * DDIM;
  float* H      = counts + G;
  float* Wfused = H + (size_t)G * 512;
  float* bvec   = Wfused + (size_t)DDIM * 512;

  // Independent precomputes first (cheap), then the BW-bound segsum, then MLP.
  // 1) Wfused = W_in @ W1                          [256, 512]
  {
    dim3 grid(512 / 64, DDIM / 64);
    gemm64_kernel<false, 0><<<grid, 256, 0, stream>>>(
        DDIM, 512, DDIM, W_in, W1, nullptr, nullptr, nullptr, Wfused);
  }
  // 2) bvec = b_in @ W1                            [512]
  bvec_kernel<<<2, 256, 0, stream>>>(b_in, W1, bvec);

  // 3) S = segment_sum(x), counts[g] = |segment g|
  segsum_kernel<<<G, 256, 0, stream>>>(x, batch, S, counts, N);

  // 4) H = relu(S @ Wfused + counts ⊗ bvec + b1)   [G, 512]
  {
    dim3 grid(512 / 64, G / 64);
    gemm64_kernel<true, 2><<<grid, 256, 0, stream>>>(
        G, 512, DDIM, S, Wfused, b1, bvec, counts, H);
  }
  // 5) out = H @ W2 + b2                           [G, 256]
  {
    dim3 grid(DDIM / 64, G / 64);
    gemm64_kernel<false, 1><<<grid, 256, 0, stream>>>(
        G, DDIM, 2 * DDIM, H, W2, b2, nullptr, nullptr, out);
  }
}